// Round 13
// baseline (42539.539 us; speedup 1.0000x reference)
//
#include <hip/hip_runtime.h>
#include <hip/hip_fp16.h>
#include <stdint.h>

#define TT 1024
#define BB 64
#define DHH 256
#define HH 512
#define G3 1536
#define CHK 256   // f16 per (g,jsl) h-chunk: [16 batches][16 j] — used by scan store & reward read

typedef _Float16 f16;
typedef _Float16 f16x4 __attribute__((ext_vector_type(4)));
typedef _Float16 f16x8 __attribute__((ext_vector_type(8)));
typedef float f32x4 __attribute__((ext_vector_type(4)));
typedef unsigned long long u64;

__device__ __forceinline__ float sigm(float x){ return 1.0f/(1.0f+__expf(-x)); }
__device__ __forceinline__ float tanh_f(float x){ return 2.0f/(1.0f+__expf(-2.0f*x)) - 1.0f; }

// ---------------- prep: f32->f16 weights, folded bias ----------------
__global__ void k_prep(const float* __restrict__ wih, const float* __restrict__ whh,
                       const float* __restrict__ bih, const float* __restrict__ bhh,
                       f16* __restrict__ wih_h, f16* __restrict__ whh_h, float* __restrict__ biasf){
  int i = blockIdx.x*256 + threadIdx.x;
  if (i < G3*HH){ wih_h[i] = (f16)wih[i]; whh_h[i] = (f16)whh[i]; }
  if (i < G3) biasf[i] = bih[i] + (i < 2*HH ? bhh[i] : 0.0f);
}

// ---------------- build x = concat(s, p.sum(axis=2)) as f16 [T*B][512] ----------------
__global__ void k_buildx(const float* __restrict__ s, const float* __restrict__ p, f16* __restrict__ x){
  int m = blockIdx.x;             // m = t*64 + b
  int t = m >> 6, b = m & 63;
  int l = threadIdx.x;            // 0..63 -> 4 floats each
  const float4* s4 = reinterpret_cast<const float4*>(s + ((size_t)b*TT + t)*DHH);
  const float4* p4 = reinterpret_cast<const float4*>(p + ((size_t)b*TT + t)*8*DHH);
  float4 sv = s4[l];
  float4 a  = p4[l];
#pragma unroll
  for (int k=1;k<8;k++){ float4 v = p4[k*64 + l]; a.x+=v.x; a.y+=v.y; a.z+=v.z; a.w+=v.w; }
  f16* xr = x + (size_t)m*HH;
  f16x4 hs = { (f16)sv.x,(f16)sv.y,(f16)sv.z,(f16)sv.w };
  f16x4 hp = { (f16)a.x,(f16)a.y,(f16)a.z,(f16)a.w };
  *reinterpret_cast<f16x4*>(xr + l*4)       = hs;
  *reinterpret_cast<f16x4*>(xr + 256 + l*4) = hp;
}

// ---------------- gi GEMM ----------------
// Writes gi chunks of 256 f16: chunk = (t*4+g)*96 + (j>>4)*3 + gate, inner = b'*16 + (j&15)
#define LDAP 72
__global__ __launch_bounds__(256) void k_gemm(const f16* __restrict__ x, const f16* __restrict__ w,
                       const float* __restrict__ biasf, f16* __restrict__ gi){
  __shared__ f16 lA[128*LDAP];
  __shared__ f16 lB[128*LDAP];
  int by = blockIdx.x;           // wrow tile (12)
  int bx = blockIdx.y;           // xrow tile (512)
  int tid = threadIdx.x, l = tid & 63, wv = tid >> 6;
  int wm = wv >> 1, wn = wv & 1;

  f32x4 acc[4][4];
#pragma unroll
  for (int i=0;i<4;i++)
#pragma unroll
    for (int j=0;j<4;j++) acc[i][j] = (f32x4){0.f,0.f,0.f,0.f};

  for (int kt = 0; kt < 8; ++kt){
#pragma unroll
    for (int r = 0; r < 4; ++r){
      int c = tid + 256*r;
      int row = c >> 3, o = c & 7;
      f16x8 va = *reinterpret_cast<const f16x8*>(w + (size_t)(by*128+row)*HH + kt*64 + o*8);
      f16x8 vb = *reinterpret_cast<const f16x8*>(x + (size_t)(bx*128+row)*HH + kt*64 + o*8);
      *reinterpret_cast<f16x8*>(&lA[row*LDAP + o*8]) = va;
      *reinterpret_cast<f16x8*>(&lB[row*LDAP + o*8]) = vb;
    }
    __syncthreads();
#pragma unroll
    for (int kk = 0; kk < 2; ++kk){
      f16x8 aF[4], bF[4];
#pragma unroll
      for (int mi=0;mi<4;mi++)
        aF[mi] = *reinterpret_cast<const f16x8*>(&lA[(wm*64+mi*16+(l&15))*LDAP + kk*32 + (l>>4)*8]);
#pragma unroll
      for (int ni=0;ni<4;ni++)
        bF[ni] = *reinterpret_cast<const f16x8*>(&lB[(wn*64+ni*16+(l&15))*LDAP + kk*32 + (l>>4)*8]);
#pragma unroll
      for (int mi=0;mi<4;mi++)
#pragma unroll
        for (int ni=0;ni<4;ni++)
          acc[mi][ni] = __builtin_amdgcn_mfma_f32_16x16x32_f16(aF[mi], bF[ni], acc[mi][ni], 0,0,0);
    }
    __syncthreads();
  }
#pragma unroll
  for (int mi=0;mi<4;mi++){
    int wrow0 = by*128 + wm*64 + mi*16 + (l>>4)*4;
    float4 bv = *reinterpret_cast<const float4*>(biasf + wrow0);
    int gate = wrow0 >> 9, j = wrow0 & 511, jhi = j >> 4, jin = j & 15;
#pragma unroll
    for (int ni=0;ni<4;ni++){
      int xrow = bx*128 + wn*64 + ni*16 + (l&15);
      int t = xrow >> 6, g = (xrow>>4)&3, bp = xrow & 15;
      size_t dst = (((size_t)t*4 + g)*96 + jhi*3 + gate)*256 + bp*16 + jin;
      union { u64 u; f16x4 h; } cv;
      cv.h = (f16x4){ (f16)(acc[mi][ni][0]+bv.x), (f16)(acc[mi][ni][1]+bv.y),
                      (f16)(acc[mi][ni][2]+bv.z), (f16)(acc[mi][ni][3]+bv.w) };
      *reinterpret_cast<u64*>(gi + dst) = cv.u;
    }
  }
}

// ---------------- GRU scan: ONE self-contained WG per batch-group (NO cross-WG comms) ----------------
// 4 WGs x 1024 thr (16 waves, 4 waves/SIMD, 512-reg/wave budget). Wave w owns j in
// [w*32, w*32+32): 96 W-row A-fragments = 384 regs. ROUND-12 FIX: the AGPR file has only
// 256 architectural names (a0-a255) — asking for 384 "+a" regs is unencodable, so the
// allocator spilled ALL of W to scratch (41 ms, ~384 scratch dword reloads/step/wave).
// Split across files: 60 frags "+a" (240 AGPR <= 256) + 36 frags "+v" (144 VGPR + ~90
// working set <= 256). MFMA reads A from either file (ISA §10). h exchange is pure LDS
// (double-buffered B-frag layout, ONE __syncthreads/step). No polls/poison/atomics.
__global__ __launch_bounds__(1024, 4) void k_scan(const f16* __restrict__ whh_h, const f16* __restrict__ gi,
                      const float* __restrict__ bhh, f16* __restrict__ hh){
  __shared__ f16 hbF[2][16][64][8];                 // 32 KB
  const int g = blockIdx.x;                         // 0..3 (16 batches each)
  const int tid = threadIdx.x;
  const int w = tid >> 6, l = tid & 63;
  const int lm = l & 15, lh = l >> 4;

  // A-fragments: rt = gate*2+q -> rows (rt>>1)*512 + w*32 + (rt&1)*16 + lm, k = kt*32 + lh*8
  f16x8 aW[6][16];
#pragma unroll
  for (int rt = 0; rt < 6; ++rt){
    const f16* wr = whh_h + ((size_t)(rt>>1)*512 + w*32 + (rt&1)*16 + lm)*HH + lh*8;
#pragma unroll
    for (int kt = 0; kt < 16; ++kt)
      aW[rt][kt] = *reinterpret_cast<const f16x8*>(wr + kt*32);
  }
  // mixed-file pin: 60 frags AGPR (240 <= 256 names), 36 frags VGPR (144)
#pragma unroll
  for (int rt = 0; rt < 6; ++rt)
#pragma unroll
    for (int kt = 0; kt < 16; ++kt){
      if (rt < 4 && kt < 15) asm volatile("" : "+a"(aW[rt][kt]));
      else                   asm volatile("" : "+v"(aW[rt][kt]));
    }

  float4 bn0 = *reinterpret_cast<const float4*>(bhh + 2*HH + w*32      + lh*4);  // q=0 n-gate b_hh
  float4 bn1 = *reinterpret_cast<const float4*>(bhh + 2*HH + w*32 + 16 + lh*4);  // q=1
  float bna[2][4] = {{bn0.x,bn0.y,bn0.z,bn0.w},{bn1.x,bn1.y,bn1.z,bn1.w}};

  union U64H { u64 u; f16x4 h; };
  U64H cA[6], cB[6], ho[2], hn[2];
  ho[0].u = 0ull; ho[1].u = 0ull;

  // gi: 6 consecutive 256-f16 chunks per (t,g,w): [q*3+gate]; lane offset lm*16 + lh*4
#define GLOAD(T_, DST) {                                                                      \
    const f16* gb_ = gi + (((size_t)(T_)*4 + g)*96 + w*6)*256 + lm*16 + lh*4;                 \
    _Pragma("unroll")                                                                         \
    for (int q6 = 0; q6 < 6; ++q6)                                                            \
      DST[q6].u = *reinterpret_cast<const u64*>(gb_ + q6*256); }

  // write h(t): LDS B-frag slots + global (chunk layout for k_reward)
#define HWRITE(T_, PAR_) {                                                                    \
    *reinterpret_cast<u64*>(&hbF[PAR_][w][lm + 16*(    (lh>>1))][(lh&1)*4]) = hn[0].u;        \
    *reinterpret_cast<u64*>(&hbF[PAR_][w][lm + 16*(2 + (lh>>1))][(lh&1)*4]) = hn[1].u;        \
    f16* hp_ = hh + (((size_t)(T_)*4 + g)*32 + w*2)*CHK + lm*16 + lh*4;                       \
    *reinterpret_cast<u64*>(hp_)       = hn[0].u;                                             \
    *reinterpret_cast<u64*>(hp_ + CHK) = hn[1].u; }

  // ---- t = 0 peel: h(-1)=0 (acc=0) ----
  {
    GLOAD(0, cA)
    GLOAD(1, cB)
#pragma unroll
    for (int q = 0; q < 2; ++q)
#pragma unroll
      for (int r = 0; r < 4; ++r){
        float rg = sigm((float)cA[q*3+0].h[r]);
        float zg = sigm((float)cA[q*3+1].h[r]);
        float ng = tanh_f((float)cA[q*3+2].h[r] + rg*bna[q][r]);
        hn[q].h[r] = (f16)((1.0f - zg)*ng);
      }
    ho[0].u = hn[0].u; ho[1].u = hn[1].u;
    HWRITE(0, 0)
    __syncthreads();
  }

  // BODY(T): MFMA on hbF[(T-1)&1]; gates with CUR=gi(T); prefetch NXT=gi(T+1); write h(T); barrier.
#define BODY(T_, CUR, NXT)                                                                    \
  {                                                                                           \
    const int t_ = (T_);                                                                      \
    const int tn_ = (t_+1 < TT) ? t_+1 : TT-1;                                                \
    GLOAD(tn_, NXT)                                                                           \
    f32x4 acc[6];                                                                             \
    _Pragma("unroll")                                                                         \
    for (int rt = 0; rt < 6; ++rt) acc[rt] = (f32x4){0.f,0.f,0.f,0.f};                        \
    _Pragma("unroll")                                                                         \
    for (int kt = 0; kt < 16; ++kt){                                                          \
      f16x8 bF = *reinterpret_cast<const f16x8*>(&hbF[(t_-1)&1][kt][l][0]);                   \
      acc[0] = __builtin_amdgcn_mfma_f32_16x16x32_f16(aW[0][kt], bF, acc[0], 0,0,0);          \
      acc[1] = __builtin_amdgcn_mfma_f32_16x16x32_f16(aW[1][kt], bF, acc[1], 0,0,0);          \
      acc[2] = __builtin_amdgcn_mfma_f32_16x16x32_f16(aW[2][kt], bF, acc[2], 0,0,0);          \
      acc[3] = __builtin_amdgcn_mfma_f32_16x16x32_f16(aW[3][kt], bF, acc[3], 0,0,0);          \
      acc[4] = __builtin_amdgcn_mfma_f32_16x16x32_f16(aW[4][kt], bF, acc[4], 0,0,0);          \
      acc[5] = __builtin_amdgcn_mfma_f32_16x16x32_f16(aW[5][kt], bF, acc[5], 0,0,0);          \
    }                                                                                         \
    _Pragma("unroll")                                                                         \
    for (int q = 0; q < 2; ++q)                                                               \
      _Pragma("unroll")                                                                       \
      for (int r = 0; r < 4; ++r){                                                            \
        float rg = sigm((float)CUR[q*3+0].h[r] + acc[q][r]);                                  \
        float zg = sigm((float)CUR[q*3+1].h[r] + acc[2+q][r]);                                \
        float ng = tanh_f((float)CUR[q*3+2].h[r] + rg*(acc[4+q][r] + bna[q][r]));             \
        hn[q].h[r] = (f16)((1.0f - zg)*ng + zg*(float)ho[q].h[r]);                            \
      }                                                                                       \
    ho[0].u = hn[0].u; ho[1].u = hn[1].u;                                                     \
    HWRITE(t_, t_&1)                                                                          \
    __syncthreads();                                                                          \
  }

  for (int t = 1; t < TT-1; t += 2){
    BODY(t,   cB, cA)
    BODY(t+1, cA, cB)
  }
  BODY(TT-1, cB, cA)
#undef BODY
#undef GLOAD
#undef HWRITE
}

// ---------------- rewards = sigmoid(h @ W_t + b_t) (chunked hh layout, stride CHK) ----------------
__global__ void k_reward(const f16* __restrict__ hh, const float* __restrict__ wt,
                         const float* __restrict__ bt, float* __restrict__ out){
  int wv = threadIdx.x >> 6, l = threadIdx.x & 63;
  int idx = blockIdx.x*4 + wv;          // idx = b*1024 + t (output order [B][T])
  int b = idx >> 10, t = idx & 1023;
  int g = b >> 4, bl = b & 15;
  const f16* hr = hh + (((size_t)t*4 + g)*32 + (l >> 1))*CHK + bl*16 + (l & 1)*8;
  f16x8 hv = *reinterpret_cast<const f16x8*>(hr);
  float4 w0 = *reinterpret_cast<const float4*>(wt + l*8);
  float4 w1 = *reinterpret_cast<const float4*>(wt + l*8 + 4);
  float sum = (float)hv[0]*w0.x + (float)hv[1]*w0.y + (float)hv[2]*w0.z + (float)hv[3]*w0.w
            + (float)hv[4]*w1.x + (float)hv[5]*w1.y + (float)hv[6]*w1.z + (float)hv[7]*w1.w;
#pragma unroll
  for (int m=32;m>=1;m>>=1) sum += __shfl_xor(sum, m);
  if (l==0) out[idx] = sigm(sum + bt[0]);
}

extern "C" void kernel_launch(void* const* d_in, const int* in_sizes, int n_in,
                              void* d_out, int out_size, void* d_ws, size_t ws_size,
                              hipStream_t stream) {
  const float* s   = (const float*)d_in[0];
  const float* p   = (const float*)d_in[1];
  const float* wih = (const float*)d_in[2];
  const float* whh = (const float*)d_in[3];
  const float* bih = (const float*)d_in[4];
  const float* bhh = (const float*)d_in[5];
  const float* wt  = (const float*)d_in[6];
  const float* bt  = (const float*)d_in[7];
  float* out = (float*)d_out;

  char* ws = (char*)d_ws;
  size_t o = 0;
  auto take = [&](size_t bytes)->char*{ char* r = ws + o; o = (o + bytes + 255) & ~(size_t)255; return r; };
  f16*      x_h   = (f16*)   take((size_t)TT*BB*HH*2);       // 67 MB
  f16*      wih_h = (f16*)   take((size_t)G3*HH*2);
  f16*      whh_h = (f16*)   take((size_t)G3*HH*2);
  float*    biasf = (float*) take((size_t)G3*4);
  f16*      gi_s  = (f16*)   take((size_t)TT*BB*G3*2);       // 201 MB
  f16*      hh    = (f16*)   take((size_t)TT*BB*HH*2);       // 67 MB, chunked layout
  (void)ws_size; (void)in_sizes; (void)n_in; (void)out_size;

  k_prep  <<<3072, 256, 0, stream>>>(wih, whh, bih, bhh, wih_h, whh_h, biasf);
  k_buildx<<<TT*BB, 64, 0, stream>>>(s, p, x_h);
  k_gemm  <<<dim3(12, 512), 256, 0, stream>>>(x_h, wih_h, biasf, gi_s);
  k_scan  <<<4, 1024, 0, stream>>>(whh_h, gi_s, bhh, hh);
  k_reward<<<TT*BB/4, 256, 0, stream>>>(hh, wt, bt, out);
}

// Round 14
// 2482.551 us; speedup vs baseline: 17.1354x; 17.1354x over previous
//
#include <hip/hip_runtime.h>
#include <hip/hip_fp16.h>
#include <stdint.h>

#define TT 1024
#define BB 64
#define DHH 256
#define HH 512
#define G3 1536
#define CHK 256   // f16 per (g,jsl) exchange chunk: [16 batches][16 j] — ONE constant for store/poll/reader

typedef _Float16 f16;
typedef _Float16 f16x4 __attribute__((ext_vector_type(4)));
typedef _Float16 f16x8 __attribute__((ext_vector_type(8)));
typedef float f32x4 __attribute__((ext_vector_type(4)));
typedef unsigned long long u64;

__device__ __forceinline__ float sigm(float x){ return 1.0f/(1.0f+__expf(-x)); }
__device__ __forceinline__ float tanh_f(float x){ return 2.0f/(1.0f+__expf(-2.0f*x)) - 1.0f; }

// ---------------- prep: f32->f16 weights, folded bias ----------------
__global__ void k_prep(const float* __restrict__ wih, const float* __restrict__ whh,
                       const float* __restrict__ bih, const float* __restrict__ bhh,
                       f16* __restrict__ wih_h, f16* __restrict__ whh_h, float* __restrict__ biasf){
  int i = blockIdx.x*256 + threadIdx.x;
  if (i < G3*HH){ wih_h[i] = (f16)wih[i]; whh_h[i] = (f16)whh[i]; }
  if (i < G3) biasf[i] = bih[i] + (i < 2*HH ? bhh[i] : 0.0f);
}

// ---------------- build x = concat(s, p.sum(axis=2)) as f16 [T*B][512] ----------------
__global__ void k_buildx(const float* __restrict__ s, const float* __restrict__ p, f16* __restrict__ x){
  int m = blockIdx.x;             // m = t*64 + b
  int t = m >> 6, b = m & 63;
  int l = threadIdx.x;            // 0..63 -> 4 floats each
  const float4* s4 = reinterpret_cast<const float4*>(s + ((size_t)b*TT + t)*DHH);
  const float4* p4 = reinterpret_cast<const float4*>(p + ((size_t)b*TT + t)*8*DHH);
  float4 sv = s4[l];
  float4 a  = p4[l];
#pragma unroll
  for (int k=1;k<8;k++){ float4 v = p4[k*64 + l]; a.x+=v.x; a.y+=v.y; a.z+=v.z; a.w+=v.w; }
  f16* xr = x + (size_t)m*HH;
  f16x4 hs = { (f16)sv.x,(f16)sv.y,(f16)sv.z,(f16)sv.w };
  f16x4 hp = { (f16)a.x,(f16)a.y,(f16)a.z,(f16)a.w };
  *reinterpret_cast<f16x4*>(xr + l*4)       = hs;
  *reinterpret_cast<f16x4*>(xr + 256 + l*4) = hp;
}

// ---------------- gi GEMM (round-8 validated layout) ----------------
// gi[((t*16+ksl)*4+g)*16 + b'][96] f16, 96 = gate*32 + j'
#define LDAP 72
__global__ __launch_bounds__(256) void k_gemm(const f16* __restrict__ x, const f16* __restrict__ w,
                       const float* __restrict__ biasf, f16* __restrict__ gi){
  __shared__ f16 lA[128*LDAP];
  __shared__ f16 lB[128*LDAP];
  int by = blockIdx.x;           // wrow tile (12)
  int bx = blockIdx.y;           // xrow tile (512)
  int tid = threadIdx.x, l = tid & 63, wv = tid >> 6;
  int wm = wv >> 1, wn = wv & 1;

  f32x4 acc[4][4];
#pragma unroll
  for (int i=0;i<4;i++)
#pragma unroll
    for (int j=0;j<4;j++) acc[i][j] = (f32x4){0.f,0.f,0.f,0.f};

  for (int kt = 0; kt < 8; ++kt){
#pragma unroll
    for (int r = 0; r < 4; ++r){
      int c = tid + 256*r;
      int row = c >> 3, o = c & 7;
      f16x8 va = *reinterpret_cast<const f16x8*>(w + (size_t)(by*128+row)*HH + kt*64 + o*8);
      f16x8 vb = *reinterpret_cast<const f16x8*>(x + (size_t)(bx*128+row)*HH + kt*64 + o*8);
      *reinterpret_cast<f16x8*>(&lA[row*LDAP + o*8]) = va;
      *reinterpret_cast<f16x8*>(&lB[row*LDAP + o*8]) = vb;
    }
    __syncthreads();
#pragma unroll
    for (int kk = 0; kk < 2; ++kk){
      f16x8 aF[4], bF[4];
#pragma unroll
      for (int mi=0;mi<4;mi++)
        aF[mi] = *reinterpret_cast<const f16x8*>(&lA[(wm*64+mi*16+(l&15))*LDAP + kk*32 + (l>>4)*8]);
#pragma unroll
      for (int ni=0;ni<4;ni++)
        bF[ni] = *reinterpret_cast<const f16x8*>(&lB[(wn*64+ni*16+(l&15))*LDAP + kk*32 + (l>>4)*8]);
#pragma unroll
      for (int mi=0;mi<4;mi++)
#pragma unroll
        for (int ni=0;ni<4;ni++)
          acc[mi][ni] = __builtin_amdgcn_mfma_f32_16x16x32_f16(aF[mi], bF[ni], acc[mi][ni], 0,0,0);
    }
    __syncthreads();
  }
#pragma unroll
  for (int mi=0;mi<4;mi++){
    int wrow0 = by*128 + wm*64 + mi*16 + (l>>4)*4;
    float4 bv = *reinterpret_cast<const float4*>(biasf + wrow0);
    int gate = wrow0 >> 9, j = wrow0 & 511, ksl = j >> 5, rp = gate*32 + (j&31);
#pragma unroll
    for (int ni=0;ni<4;ni++){
      int xrow = bx*128 + wn*64 + ni*16 + (l&15);
      int t = xrow >> 6, g = (xrow>>4)&3, bp = xrow & 15;
      size_t dst = ((((size_t)t*16 + ksl)*4 + g)*16 + bp)*96 + rp;
      union { u64 u; f16x4 h; } cv;
      cv.h = (f16x4){ (f16)(acc[mi][ni][0]+bv.x), (f16)(acc[mi][ni][1]+bv.y),
                      (f16)(acc[mi][ni][2]+bv.z), (f16)(acc[mi][ni][3]+bv.w) };
      *reinterpret_cast<u64*>(gi + dst) = cv.u;
    }
  }
}

// ---------------- persistent GRU scan: barrier-free direct B-fragment poll ----------------
// 128 single-wave WGs: group g = bid&3 (16 batches), j-slice jsl = bid>>2 (16 j).
// 48 W rows in 192 AGPRs ("+a", fits the 256-name a-file; ~330 total regs <= 512 @ 1 wave/SIMD).
// h layout hh[t][g][jsl][b16][16j] (CHK=256 f16): producer wave stores one contiguous 512B
// chunk (1 u64/lane). Consumer polls its MFMA B-fragments DIRECTLY: lane (lm,lh), kt ->
// chunk 2kt+(lh>>1), byte lm*32+(lh&1)*16 — the 16B loaded ARE the B-operand. No LDS, no
// barrier, no staging: waves fully decoupled (r8's 4-wave barrier max-coupling removed).
// Poll-the-data (proven r3-r8): hh poisoned 0xFF; finite h never yields f16 0xFFFF; each u64
// is one relaxed agent-atomic store (all-or-nothing); pure dataflow -> no livelock possible.
// gi software-pipelined depth 2, ISSUED BEFORE the poll so HBM latency rides the poll wait.
__global__ __launch_bounds__(64, 1) void k_scan(const f16* __restrict__ whh_h, const f16* __restrict__ gi,
                      const float* __restrict__ bhh, f16* __restrict__ hh){
  const int bid = blockIdx.x;                       // 0..127
  const int g = bid & 3, jsl = bid >> 2;            // group, j-slice 0..31
  const int l = threadIdx.x, lm = l & 15, lh = l >> 4;

  // persistent A-fragments: aW[gate][kt], W row = gate*512 + jsl*16 + lm, k = kt*32 + lh*8
  f16x8 aW[3][16];
#pragma unroll
  for (int gate = 0; gate < 3; ++gate){
    const f16* wr = whh_h + ((size_t)gate*512 + jsl*16 + lm)*HH + lh*8;
#pragma unroll
    for (int kt = 0; kt < 16; ++kt)
      aW[gate][kt] = *reinterpret_cast<const f16x8*>(wr + kt*32);
  }
#pragma unroll
  for (int gate = 0; gate < 3; ++gate)
#pragma unroll
    for (int kt = 0; kt < 16; ++kt)
      asm volatile("" : "+a"(aW[gate][kt]));        // 192 AGPR <= 256-name file: legal, resident

  float4 bnv = *reinterpret_cast<const float4*>(bhh + 2*HH + jsl*16 + lh*4);
  float bna[4] = {bnv.x, bnv.y, bnv.z, bnv.w};
  const int ksl2 = jsl >> 1, jo = (jsl & 1)*16 + lh*4;     // gi addressing (r8-validated)

  union U64H { u64 u; f16x4 h; };
  union BFR  { u64 q[2]; f16x8 v8; };
  U64H cA[3], cB[3], cC[3], ho, hn;
  ho.u = 0ull;

#define GLOAD(T_, DST) {                                                                      \
    const f16* gb_ = gi + ((((size_t)(T_)*16 + ksl2)*4 + g)*16 + lm)*96;                      \
    DST[0].u = *reinterpret_cast<const u64*>(gb_ + jo);                                       \
    DST[1].u = *reinterpret_cast<const u64*>(gb_ + 32 + jo);                                  \
    DST[2].u = *reinterpret_cast<const u64*>(gb_ + 64 + jo); }

#define PUBLISH(T_, HN)                                                                       \
    __hip_atomic_store(reinterpret_cast<u64*>(hh + (((size_t)(T_)*4 + g)*32 + jsl)*CHK        \
                       + lm*16 + lh*4), HN.u, __ATOMIC_RELAXED, __HIP_MEMORY_SCOPE_AGENT);

  // ---- t = 0 peel: h_{-1}=0; fill gi pipeline ----
  {
    GLOAD(0, cA) GLOAD(1, cB) GLOAD(2, cC)
#pragma unroll
    for (int r = 0; r < 4; ++r){
      float rg = sigm((float)cA[0].h[r]);
      float zg = sigm((float)cA[1].h[r]);
      float ng = tanh_f((float)cA[2].h[r] + rg*bna[r]);
      hn.h[r] = (f16)((1.0f - zg)*ng);
    }
    ho.u = hn.u;
    PUBLISH(0, hn)
  }

  // BODY(T): issue gi(T+2); poll B-frags of h(T-1) directly; MFMA; gates; publish h(T).
#define BODY(T_, CUR, NXT2)                                                                   \
  {                                                                                           \
    const int t_ = (T_);                                                                      \
    { const int tn_ = (t_+2 < TT) ? t_+2 : TT-1; GLOAD(tn_, NXT2) }                           \
    BFR bF[16];                                                                               \
    const u64* pq = reinterpret_cast<const u64*>(                                             \
        reinterpret_cast<const char*>(hh + (((size_t)(t_-1)*4 + g)*32)*CHK)                   \
        + (lh>>1)*512 + lm*32 + (lh&1)*16);                                                   \
    int ok;                                                                                   \
    do {                                                                                      \
      ok = 1;                                                                                 \
      _Pragma("unroll")                                                                       \
      for (int kt = 0; kt < 16; ++kt){                                                        \
        bF[kt].q[0] = __hip_atomic_load(pq + (size_t)kt*128,     __ATOMIC_RELAXED, __HIP_MEMORY_SCOPE_AGENT); \
        bF[kt].q[1] = __hip_atomic_load(pq + (size_t)kt*128 + 1, __ATOMIC_RELAXED, __HIP_MEMORY_SCOPE_AGENT); \
        ok &= (int)((unsigned)bF[kt].q[0] != 0xFFFFFFFFu);                                    \
        ok &= (int)((unsigned)bF[kt].q[1] != 0xFFFFFFFFu);                                    \
      }                                                                                       \
    } while (!__all(ok));                                                                     \
    f32x4 aR = (f32x4){0.f,0.f,0.f,0.f};                                                      \
    f32x4 aZ = (f32x4){0.f,0.f,0.f,0.f};                                                      \
    f32x4 aN = (f32x4){0.f,0.f,0.f,0.f};                                                      \
    _Pragma("unroll")                                                                         \
    for (int kt = 0; kt < 16; ++kt){                                                          \
      aR = __builtin_amdgcn_mfma_f32_16x16x32_f16(aW[0][kt], bF[kt].v8, aR, 0,0,0);           \
      aZ = __builtin_amdgcn_mfma_f32_16x16x32_f16(aW[1][kt], bF[kt].v8, aZ, 0,0,0);           \
      aN = __builtin_amdgcn_mfma_f32_16x16x32_f16(aW[2][kt], bF[kt].v8, aN, 0,0,0);           \
    }                                                                                         \
    _Pragma("unroll")                                                                         \
    for (int r = 0; r < 4; ++r){                                                              \
      float rg = sigm((float)CUR[0].h[r] + aR[r]);                                            \
      float zg = sigm((float)CUR[1].h[r] + aZ[r]);                                            \
      float ng = tanh_f((float)CUR[2].h[r] + rg*(aN[r] + bna[r]));                            \
      hn.h[r] = (f16)((1.0f - zg)*ng + zg*(float)ho.h[r]);                                    \
    }                                                                                         \
    ho.u = hn.u;                                                                              \
    PUBLISH(t_, hn)                                                                           \
  }

  // t = 1..1023 in 341 triples, 3-buffer gi rotation
  for (int t = 1; t < TT; t += 3){
    BODY(t,   cB, cA)
    BODY(t+1, cC, cB)
    BODY(t+2, cA, cC)
  }
#undef BODY
#undef GLOAD
#undef PUBLISH
}

// ---------------- rewards = sigmoid(h @ W_t + b_t) (chunked hh layout, stride CHK) ----------------
__global__ void k_reward(const f16* __restrict__ hh, const float* __restrict__ wt,
                         const float* __restrict__ bt, float* __restrict__ out){
  int wv = threadIdx.x >> 6, l = threadIdx.x & 63;
  int idx = blockIdx.x*4 + wv;          // idx = b*1024 + t (output order [B][T])
  int b = idx >> 10, t = idx & 1023;
  int g = b >> 4, bl = b & 15;
  const f16* hr = hh + (((size_t)t*4 + g)*32 + (l >> 1))*CHK + bl*16 + (l & 1)*8;
  f16x8 hv = *reinterpret_cast<const f16x8*>(hr);
  float4 w0 = *reinterpret_cast<const float4*>(wt + l*8);
  float4 w1 = *reinterpret_cast<const float4*>(wt + l*8 + 4);
  float sum = (float)hv[0]*w0.x + (float)hv[1]*w0.y + (float)hv[2]*w0.z + (float)hv[3]*w0.w
            + (float)hv[4]*w1.x + (float)hv[5]*w1.y + (float)hv[6]*w1.z + (float)hv[7]*w1.w;
#pragma unroll
  for (int m=32;m>=1;m>>=1) sum += __shfl_xor(sum, m);
  if (l==0) out[idx] = sigm(sum + bt[0]);
}

extern "C" void kernel_launch(void* const* d_in, const int* in_sizes, int n_in,
                              void* d_out, int out_size, void* d_ws, size_t ws_size,
                              hipStream_t stream) {
  const float* s   = (const float*)d_in[0];
  const float* p   = (const float*)d_in[1];
  const float* wih = (const float*)d_in[2];
  const float* whh = (const float*)d_in[3];
  const float* bih = (const float*)d_in[4];
  const float* bhh = (const float*)d_in[5];
  const float* wt  = (const float*)d_in[6];
  const float* bt  = (const float*)d_in[7];
  float* out = (float*)d_out;

  char* ws = (char*)d_ws;
  size_t o = 0;
  auto take = [&](size_t bytes)->char*{ char* r = ws + o; o = (o + bytes + 255) & ~(size_t)255; return r; };
  f16*      x_h   = (f16*)   take((size_t)TT*BB*HH*2);       // 67 MB
  f16*      wih_h = (f16*)   take((size_t)G3*HH*2);
  f16*      whh_h = (f16*)   take((size_t)G3*HH*2);
  float*    biasf = (float*) take((size_t)G3*4);
  f16*      gi_s  = (f16*)   take((size_t)TT*BB*G3*2);       // 201 MB
  f16*      hh    = (f16*)   take((size_t)TT*BB*HH*2);       // 67 MB, chunked layout
  (void)ws_size; (void)in_sizes; (void)n_in; (void)out_size;

  hipMemsetAsync(hh, 0xFF, (size_t)TT*BB*HH*2, stream);      // poison: poll-the-data sentinel
  k_prep  <<<3072, 256, 0, stream>>>(wih, whh, bih, bhh, wih_h, whh_h, biasf);
  k_buildx<<<TT*BB, 64, 0, stream>>>(s, p, x_h);
  k_gemm  <<<dim3(12, 512), 256, 0, stream>>>(x_h, wih_h, biasf, gi_s);
  k_scan  <<<128, 64, 0, stream>>>(whh_h, gi_s, bhh, hh);
  k_reward<<<TT*BB/4, 256, 0, stream>>>(hh, wt, bt, out);
}

// Round 15
// 2467.737 us; speedup vs baseline: 17.2383x; 1.0060x over previous
//
#include <hip/hip_runtime.h>
#include <hip/hip_fp16.h>
#include <stdint.h>

#define TT 1024
#define BB 64
#define DHH 256
#define HH 512
#define G3 1536
#define CHK 256   // f16 per (g,jsl) exchange chunk: [16 batches][16 j]
#define RNG 8     // exchange ring depth (drift<2 steps; poison margin 4; poll margin 5)

typedef _Float16 f16;
typedef _Float16 f16x4 __attribute__((ext_vector_type(4)));
typedef _Float16 f16x8 __attribute__((ext_vector_type(8)));
typedef float f32x4 __attribute__((ext_vector_type(4)));
typedef unsigned long long u64;

__device__ __forceinline__ float sigm(float x){ return 1.0f/(1.0f+__expf(-x)); }
__device__ __forceinline__ float tanh_f(float x){ return 2.0f/(1.0f+__expf(-2.0f*x)) - 1.0f; }

// ---------------- prep: f32->f16 weights, folded bias ----------------
__global__ void k_prep(const float* __restrict__ wih, const float* __restrict__ whh,
                       const float* __restrict__ bih, const float* __restrict__ bhh,
                       f16* __restrict__ wih_h, f16* __restrict__ whh_h, float* __restrict__ biasf){
  int i = blockIdx.x*256 + threadIdx.x;
  if (i < G3*HH){ wih_h[i] = (f16)wih[i]; whh_h[i] = (f16)whh[i]; }
  if (i < G3) biasf[i] = bih[i] + (i < 2*HH ? bhh[i] : 0.0f);
}

// ---------------- build x = concat(s, p.sum(axis=2)) as f16 [T*B][512] ----------------
__global__ void k_buildx(const float* __restrict__ s, const float* __restrict__ p, f16* __restrict__ x){
  int m = blockIdx.x;             // m = t*64 + b
  int t = m >> 6, b = m & 63;
  int l = threadIdx.x;            // 0..63 -> 4 floats each
  const float4* s4 = reinterpret_cast<const float4*>(s + ((size_t)b*TT + t)*DHH);
  const float4* p4 = reinterpret_cast<const float4*>(p + ((size_t)b*TT + t)*8*DHH);
  float4 sv = s4[l];
  float4 a  = p4[l];
#pragma unroll
  for (int k=1;k<8;k++){ float4 v = p4[k*64 + l]; a.x+=v.x; a.y+=v.y; a.z+=v.z; a.w+=v.w; }
  f16* xr = x + (size_t)m*HH;
  f16x4 hs = { (f16)sv.x,(f16)sv.y,(f16)sv.z,(f16)sv.w };
  f16x4 hp = { (f16)a.x,(f16)a.y,(f16)a.z,(f16)a.w };
  *reinterpret_cast<f16x4*>(xr + l*4)       = hs;
  *reinterpret_cast<f16x4*>(xr + 256 + l*4) = hp;
}

// ---------------- gi GEMM (round-8 validated layout) ----------------
// gi[((t*16+ksl)*4+g)*16 + b'][96] f16, 96 = gate*32 + j'
#define LDAP 72
__global__ __launch_bounds__(256) void k_gemm(const f16* __restrict__ x, const f16* __restrict__ w,
                       const float* __restrict__ biasf, f16* __restrict__ gi){
  __shared__ f16 lA[128*LDAP];
  __shared__ f16 lB[128*LDAP];
  int by = blockIdx.x;           // wrow tile (12)
  int bx = blockIdx.y;           // xrow tile (512)
  int tid = threadIdx.x, l = tid & 63, wv = tid >> 6;
  int wm = wv >> 1, wn = wv & 1;

  f32x4 acc[4][4];
#pragma unroll
  for (int i=0;i<4;i++)
#pragma unroll
    for (int j=0;j<4;j++) acc[i][j] = (f32x4){0.f,0.f,0.f,0.f};

  for (int kt = 0; kt < 8; ++kt){
#pragma unroll
    for (int r = 0; r < 4; ++r){
      int c = tid + 256*r;
      int row = c >> 3, o = c & 7;
      f16x8 va = *reinterpret_cast<const f16x8*>(w + (size_t)(by*128+row)*HH + kt*64 + o*8);
      f16x8 vb = *reinterpret_cast<const f16x8*>(x + (size_t)(bx*128+row)*HH + kt*64 + o*8);
      *reinterpret_cast<f16x8*>(&lA[row*LDAP + o*8]) = va;
      *reinterpret_cast<f16x8*>(&lB[row*LDAP + o*8]) = vb;
    }
    __syncthreads();
#pragma unroll
    for (int kk = 0; kk < 2; ++kk){
      f16x8 aF[4], bF[4];
#pragma unroll
      for (int mi=0;mi<4;mi++)
        aF[mi] = *reinterpret_cast<const f16x8*>(&lA[(wm*64+mi*16+(l&15))*LDAP + kk*32 + (l>>4)*8]);
#pragma unroll
      for (int ni=0;ni<4;ni++)
        bF[ni] = *reinterpret_cast<const f16x8*>(&lB[(wn*64+ni*16+(l&15))*LDAP + kk*32 + (l>>4)*8]);
#pragma unroll
      for (int mi=0;mi<4;mi++)
#pragma unroll
        for (int ni=0;ni<4;ni++)
          acc[mi][ni] = __builtin_amdgcn_mfma_f32_16x16x32_f16(aF[mi], bF[ni], acc[mi][ni], 0,0,0);
    }
    __syncthreads();
  }
#pragma unroll
  for (int mi=0;mi<4;mi++){
    int wrow0 = by*128 + wm*64 + mi*16 + (l>>4)*4;
    float4 bv = *reinterpret_cast<const float4*>(biasf + wrow0);
    int gate = wrow0 >> 9, j = wrow0 & 511, ksl = j >> 5, rp = gate*32 + (j&31);
#pragma unroll
    for (int ni=0;ni<4;ni++){
      int xrow = bx*128 + wn*64 + ni*16 + (l&15);
      int t = xrow >> 6, g = (xrow>>4)&3, bp = xrow & 15;
      size_t dst = ((((size_t)t*16 + ksl)*4 + g)*16 + bp)*96 + rp;
      union { u64 u; f16x4 h; } cv;
      cv.h = (f16x4){ (f16)(acc[mi][ni][0]+bv.x), (f16)(acc[mi][ni][1]+bv.y),
                      (f16)(acc[mi][ni][2]+bv.z), (f16)(acc[mi][ni][3]+bv.w) };
      *reinterpret_cast<u64*>(gi + dst) = cv.u;
    }
  }
}

// ---------------- persistent GRU scan: barrier-free poll on L3-PINNED RING ----------------
// r14 structure (barrier-free direct B-fragment poll, 48 W rows in 192 AGPRs) + ONE change:
// the exchange moves from the 67MB hh stream (evicted to HBM between publish and poll — the
// ~80MB FETCH overshoot and ~900cy poll rounds of r14) to a 512KB 8-deep ring hring[t&7],
// permanently MALL-resident -> every poll round is an L3 hit. History hh[t] (for k_reward) is
// written by a PLAIN fire-and-forget store, off the critical path (cross-kernel visibility via
// dispatch boundary, same as gi). Slot recycling is race-free by the drift bound (no wave can
// start step t before all published t-1 => drift < 2 steps): BODY(t) re-poisons its own chunk
// of slot (t+4)&7 — data t-4, consumed >=2 steps ago; next written at t+4, next polled at t+5.
// The poison is an agent-atomic store (plain stores can linger CU-side while polls read MALL).
__global__ __launch_bounds__(64, 1) void k_scan(const f16* __restrict__ whh_h, const f16* __restrict__ gi,
                      const float* __restrict__ bhh, f16* __restrict__ hh, f16* __restrict__ hring){
  const int bid = blockIdx.x;                       // 0..127
  const int g = bid & 3, jsl = bid >> 2;            // group, j-slice 0..31
  const int l = threadIdx.x, lm = l & 15, lh = l >> 4;

  // persistent A-fragments: aW[gate][kt], W row = gate*512 + jsl*16 + lm, k = kt*32 + lh*8
  f16x8 aW[3][16];
#pragma unroll
  for (int gate = 0; gate < 3; ++gate){
    const f16* wr = whh_h + ((size_t)gate*512 + jsl*16 + lm)*HH + lh*8;
#pragma unroll
    for (int kt = 0; kt < 16; ++kt)
      aW[gate][kt] = *reinterpret_cast<const f16x8*>(wr + kt*32);
  }
#pragma unroll
  for (int gate = 0; gate < 3; ++gate)
#pragma unroll
    for (int kt = 0; kt < 16; ++kt)
      asm volatile("" : "+a"(aW[gate][kt]));        // 192 AGPR <= 256-name file: resident (r14-proven)

  float4 bnv = *reinterpret_cast<const float4*>(bhh + 2*HH + jsl*16 + lh*4);
  float bna[4] = {bnv.x, bnv.y, bnv.z, bnv.w};
  const int ksl2 = jsl >> 1, jo = (jsl & 1)*16 + lh*4;     // gi addressing (r8-validated)
  const size_t pofs = (size_t)lm*16 + lh*4;                // producer f16 offset in chunk

  union U64H { u64 u; f16x4 h; };
  union BFR  { u64 q[2]; f16x8 v8; };
  U64H cA[3], cB[3], cC[3], ho, hn;
  ho.u = 0ull;

#define GLOAD(T_, DST) {                                                                      \
    const f16* gb_ = gi + ((((size_t)(T_)*16 + ksl2)*4 + g)*16 + lm)*96;                      \
    DST[0].u = *reinterpret_cast<const u64*>(gb_ + jo);                                       \
    DST[1].u = *reinterpret_cast<const u64*>(gb_ + 32 + jo);                                  \
    DST[2].u = *reinterpret_cast<const u64*>(gb_ + 64 + jo); }

  // publish: ring (atomic, MALL, critical path) + history (plain, lazy, for k_reward)
#define PUBLISH(T_, HN) {                                                                     \
    __hip_atomic_store(reinterpret_cast<u64*>(hring + ((((size_t)((T_)&7))*4 + g)*32 + jsl)*CHK \
                       + pofs), HN.u, __ATOMIC_RELAXED, __HIP_MEMORY_SCOPE_AGENT);            \
    *reinterpret_cast<u64*>(hh + (((size_t)(T_)*4 + g)*32 + jsl)*CHK + pofs) = HN.u; }

  // ---- t = 0 peel: h_{-1}=0; fill gi pipeline ----
  {
    GLOAD(0, cA) GLOAD(1, cB) GLOAD(2, cC)
#pragma unroll
    for (int r = 0; r < 4; ++r){
      float rg = sigm((float)cA[0].h[r]);
      float zg = sigm((float)cA[1].h[r]);
      float ng = tanh_f((float)cA[2].h[r] + rg*bna[r]);
      hn.h[r] = (f16)((1.0f - zg)*ng);
    }
    ho.u = hn.u;
    PUBLISH(0, hn)
  }

  // BODY(T): poison slot (T+4)&7 (own chunk); issue gi(T+2); poll B-frags of h(T-1) from ring;
  // MFMA; gates; publish h(T).
#define BODY(T_, CUR, NXT2)                                                                   \
  {                                                                                           \
    const int t_ = (T_);                                                                      \
    __hip_atomic_store(reinterpret_cast<u64*>(hring + ((((size_t)((t_+4)&7))*4 + g)*32 + jsl)*CHK \
                       + pofs), 0xFFFFFFFFFFFFFFFFull, __ATOMIC_RELAXED, __HIP_MEMORY_SCOPE_AGENT); \
    { const int tn_ = (t_+2 < TT) ? t_+2 : TT-1; GLOAD(tn_, NXT2) }                           \
    BFR bF[16];                                                                               \
    const u64* pq = reinterpret_cast<const u64*>(                                             \
        reinterpret_cast<const char*>(hring + ((((size_t)((t_-1)&7))*4 + g)*32)*CHK)          \
        + (lh>>1)*512 + lm*32 + (lh&1)*16);                                                   \
    int ok;                                                                                   \
    do {                                                                                      \
      ok = 1;                                                                                 \
      _Pragma("unroll")                                                                       \
      for (int kt = 0; kt < 16; ++kt){                                                        \
        bF[kt].q[0] = __hip_atomic_load(pq + (size_t)kt*128,     __ATOMIC_RELAXED, __HIP_MEMORY_SCOPE_AGENT); \
        bF[kt].q[1] = __hip_atomic_load(pq + (size_t)kt*128 + 1, __ATOMIC_RELAXED, __HIP_MEMORY_SCOPE_AGENT); \
        ok &= (int)((unsigned)bF[kt].q[0] != 0xFFFFFFFFu);                                    \
        ok &= (int)((unsigned)bF[kt].q[1] != 0xFFFFFFFFu);                                    \
      }                                                                                       \
    } while (!__all(ok));                                                                     \
    f32x4 aR = (f32x4){0.f,0.f,0.f,0.f};                                                      \
    f32x4 aZ = (f32x4){0.f,0.f,0.f,0.f};                                                      \
    f32x4 aN = (f32x4){0.f,0.f,0.f,0.f};                                                      \
    _Pragma("unroll")                                                                         \
    for (int kt = 0; kt < 16; ++kt){                                                          \
      aR = __builtin_amdgcn_mfma_f32_16x16x32_f16(aW[0][kt], bF[kt].v8, aR, 0,0,0);           \
      aZ = __builtin_amdgcn_mfma_f32_16x16x32_f16(aW[1][kt], bF[kt].v8, aZ, 0,0,0);           \
      aN = __builtin_amdgcn_mfma_f32_16x16x32_f16(aW[2][kt], bF[kt].v8, aN, 0,0,0);           \
    }                                                                                         \
    _Pragma("unroll")                                                                         \
    for (int r = 0; r < 4; ++r){                                                              \
      float rg = sigm((float)CUR[0].h[r] + aR[r]);                                            \
      float zg = sigm((float)CUR[1].h[r] + aZ[r]);                                            \
      float ng = tanh_f((float)CUR[2].h[r] + rg*(aN[r] + bna[r]));                            \
      hn.h[r] = (f16)((1.0f - zg)*ng + zg*(float)ho.h[r]);                                    \
    }                                                                                         \
    ho.u = hn.u;                                                                              \
    PUBLISH(t_, hn)                                                                           \
  }

  // t = 1..1023 in 341 triples, 3-buffer gi rotation
  for (int t = 1; t < TT; t += 3){
    BODY(t,   cB, cA)
    BODY(t+1, cC, cB)
    BODY(t+2, cA, cC)
  }
#undef BODY
#undef GLOAD
#undef PUBLISH
}

// ---------------- rewards = sigmoid(h @ W_t + b_t) (chunked hh layout, stride CHK) ----------------
__global__ void k_reward(const f16* __restrict__ hh, const float* __restrict__ wt,
                         const float* __restrict__ bt, float* __restrict__ out){
  int wv = threadIdx.x >> 6, l = threadIdx.x & 63;
  int idx = blockIdx.x*4 + wv;          // idx = b*1024 + t (output order [B][T])
  int b = idx >> 10, t = idx & 1023;
  int g = b >> 4, bl = b & 15;
  const f16* hr = hh + (((size_t)t*4 + g)*32 + (l >> 1))*CHK + bl*16 + (l & 1)*8;
  f16x8 hv = *reinterpret_cast<const f16x8*>(hr);
  float4 w0 = *reinterpret_cast<const float4*>(wt + l*8);
  float4 w1 = *reinterpret_cast<const float4*>(wt + l*8 + 4);
  float sum = (float)hv[0]*w0.x + (float)hv[1]*w0.y + (float)hv[2]*w0.z + (float)hv[3]*w0.w
            + (float)hv[4]*w1.x + (float)hv[5]*w1.y + (float)hv[6]*w1.z + (float)hv[7]*w1.w;
#pragma unroll
  for (int m=32;m>=1;m>>=1) sum += __shfl_xor(sum, m);
  if (l==0) out[idx] = sigm(sum + bt[0]);
}

extern "C" void kernel_launch(void* const* d_in, const int* in_sizes, int n_in,
                              void* d_out, int out_size, void* d_ws, size_t ws_size,
                              hipStream_t stream) {
  const float* s   = (const float*)d_in[0];
  const float* p   = (const float*)d_in[1];
  const float* wih = (const float*)d_in[2];
  const float* whh = (const float*)d_in[3];
  const float* bih = (const float*)d_in[4];
  const float* bhh = (const float*)d_in[5];
  const float* wt  = (const float*)d_in[6];
  const float* bt  = (const float*)d_in[7];
  float* out = (float*)d_out;

  char* ws = (char*)d_ws;
  size_t o = 0;
  auto take = [&](size_t bytes)->char*{ char* r = ws + o; o = (o + bytes + 255) & ~(size_t)255; return r; };
  f16*      x_h   = (f16*)   take((size_t)TT*BB*HH*2);       // 67 MB
  f16*      wih_h = (f16*)   take((size_t)G3*HH*2);
  f16*      whh_h = (f16*)   take((size_t)G3*HH*2);
  float*    biasf = (float*) take((size_t)G3*4);
  f16*      gi_s  = (f16*)   take((size_t)TT*BB*G3*2);       // 201 MB
  f16*      hh    = (f16*)   take((size_t)TT*BB*HH*2);       // 67 MB history (plain stores)
  f16*      hring = (f16*)   take((size_t)RNG*4*32*CHK*2);   // 512 KB MALL-resident exchange ring
  (void)ws_size; (void)in_sizes; (void)n_in; (void)out_size;

  hipMemsetAsync(hring, 0xFF, (size_t)RNG*4*32*CHK*2, stream);  // poison the ring only
  k_prep  <<<3072, 256, 0, stream>>>(wih, whh, bih, bhh, wih_h, whh_h, biasf);
  k_buildx<<<TT*BB, 64, 0, stream>>>(s, p, x_h);
  k_gemm  <<<dim3(12, 512), 256, 0, stream>>>(x_h, wih_h, biasf, gi_s);
  k_scan  <<<128, 64, 0, stream>>>(whh_h, gi_s, bhh, hh, hring);
  k_reward<<<TT*BB/4, 256, 0, stream>>>(hh, wt, bt, out);
}